// Round 1
// baseline (363972.876 us; speedup 1.0000x reference)
//
#include <hip/hip_runtime.h>
#include <hip/hip_bf16.h>

#define TSTEPS 8192
#define HDIM   1024
#define FUT    16

typedef unsigned short bfu;
typedef __bf16 bf8v  __attribute__((ext_vector_type(8)));
typedef float  f32x4 __attribute__((ext_vector_type(4)));

__device__ __forceinline__ float u2lo(unsigned u){ return __uint_as_float(u << 16); }
__device__ __forceinline__ float u2hi(unsigned u){ return __uint_as_float(u & 0xffff0000u); }
__device__ __forceinline__ bfu f2bfu(float f){
  unsigned u = __float_as_uint(f);
  return (bfu)((u + 0x7fffu + ((u >> 16) & 1u)) >> 16);   // RNE
}
__device__ __forceinline__ ushort4 pack4(float4 v){
  ushort4 p; p.x = f2bfu(v.x); p.y = f2bfu(v.y); p.z = f2bfu(v.z); p.w = f2bfu(v.w); return p;
}
__device__ __forceinline__ float leaky(float v){ return v >= 0.f ? v : 0.8f * v; }
__device__ __forceinline__ float sigm(float v){ return 1.f / (1.f + expf(-v)); }

// ---- grid-wide flag sync (persistent kernels; all blocks resident) ----
__device__ __forceinline__ void gwait(int* flags, int target, int nflags){
  if (threadIdx.x < 64) {
    for (;;) {
      int ok = 1;
      for (int i = 0; i < nflags; i += 64)
        if (__hip_atomic_load(flags + threadIdx.x + i, __ATOMIC_RELAXED,
                              __HIP_MEMORY_SCOPE_AGENT) < target) ok = 0;
      if (ok) break;
      __builtin_amdgcn_s_sleep(1);
    }
  }
  __syncthreads();
  __threadfence();   // acquire: invalidate stale L1/L2 before reading h
}
__device__ __forceinline__ void gpost(int* flags, int val){
  __syncthreads();
  if (threadIdx.x == 0) {
    __threadfence(); // release: drain h stores to coherent point
    __hip_atomic_store(flags + blockIdx.x, val, __ATOMIC_RELAXED,
                       __HIP_MEMORY_SCOPE_AGENT);
  }
}

// ================= persistent LSTM recurrence =================
// 512 blocks x 256 thr. Block b owns L0 units {2b,2b+1} (waves 0,1) and
// L1 units {2b,2b+1} (waves 2,3). Fused step t: layer0@t + layer1@(t-1)
// -> 1 grid sync/step. Weights bf16 in LDS (~58KB -> 2 blocks/CU, all resident).
__global__ __launch_bounds__(256, 1) void lstm_seq(
    const float* __restrict__ x,
    const float* __restrict__ Wih0, const float* __restrict__ Whh0,
    const float* __restrict__ bih0, const float* __restrict__ bhh0,
    const float* __restrict__ Wih1, const float* __restrict__ Whh1,
    const float* __restrict__ bih1, const float* __restrict__ bhh1,
    bfu* __restrict__ hsbf, float* __restrict__ h0buf, float* __restrict__ h1buf,
    int* __restrict__ flagA,
    float* __restrict__ c0s, float* __restrict__ c1s,
    float* __restrict__ h0f, float* __restrict__ h1f)
{
  __shared__ bfu   w0l[8 * 1024];   // L0: 2 units x 4 gates x 1024 (bf16)
  __shared__ bfu   w1l[8 * 2048];   // L1: 2 units x 4 gates x [Wih1|Whh1]
  __shared__ float hcat[2048];      // [h0prev | h1prevprev] fp32
  __shared__ float xs[16];
  __shared__ float wx[8][16];       // Wih0 rows (15 cols)

  const int tid  = threadIdx.x;
  const int b    = blockIdx.x;
  const int wv   = tid >> 6;
  const int lane = tid & 63;

  // ---- preload weights (fp32 -> bf16, coalesced row sweeps) ----
  for (int idx = tid * 4; idx < 8 * 1024; idx += 1024) {
    int r = idx >> 10, k = idx & 1023;
    int gr = ((r & 3) << 10) + (b << 1) + (r >> 2);
    float4 v = *(const float4*)(Whh0 + (size_t)gr * 1024 + k);
    *(ushort4*)(w0l + idx) = pack4(v);
  }
  for (int idx = tid * 4; idx < 8 * 2048; idx += 1024) {
    int r = idx >> 11, k = idx & 2047;
    int gr = ((r & 3) << 10) + (b << 1) + (r >> 2);
    float4 v = (k < 1024) ? *(const float4*)(Wih1 + (size_t)gr * 1024 + k)
                          : *(const float4*)(Whh1 + (size_t)gr * 1024 + (k - 1024));
    *(ushort4*)(w1l + idx) = pack4(v);
  }
  if (tid < 120) {
    int r = tid / 15, k = tid - r * 15;
    int gr = ((r & 3) << 10) + (b << 1) + (r >> 2);
    wx[r][k] = Wih0[gr * 15 + k];
  }
  float bs[4];
  if (lane == 0) {
    #pragma unroll
    for (int g = 0; g < 4; ++g) {
      if (wv < 2) { int gr = (g << 10) + (b << 1) + wv;        bs[g] = bih0[gr] + bhh0[gr]; }
      else        { int gr = (g << 10) + (b << 1) + (wv - 2);  bs[g] = bih1[gr] + bhh1[gr]; }
    }
  }
  float cc = 0.f, hv = 0.f;   // cell/h state for this wave's unit (lane0)
  __syncthreads();

  for (int t = 0; t <= TSTEPS; ++t) {
    gwait(flagA, t, 512);
    // stage h0[t-1], h1[t-2] into LDS (fp32)
    {
      int base = tid * 8;
      const float* src = (tid < 128) ? (h0buf + ((t + 1) & 1) * HDIM + base)
                                     : (h1buf + (t & 1) * HDIM + (base - 1024));
      float4* dst = (float4*)(hcat + base);
      dst[0] = *(const float4*)src;
      dst[1] = *(const float4*)(src + 4);
    }
    if (tid < 15 && t < TSTEPS) xs[tid] = x[t * 15 + tid];
    __syncthreads();

    float a[4] = {0.f, 0.f, 0.f, 0.f};
    if (wv < 2) {                       // ---- layer0 @ t : Whh0 . h0[t-1]
      #pragma unroll
      for (int p = 0; p < 2; ++p) {
        int k = p * 512 + lane * 8;
        float4 ha = *(const float4*)(hcat + k);
        float4 hb = *(const float4*)(hcat + k + 4);
        #pragma unroll
        for (int g = 0; g < 4; ++g) {
          uint4 wc = *(const uint4*)(w0l + (((wv << 2) + g) << 10) + k);
          float s = a[g];
          s = fmaf(u2lo(wc.x), ha.x, s); s = fmaf(u2hi(wc.x), ha.y, s);
          s = fmaf(u2lo(wc.y), ha.z, s); s = fmaf(u2hi(wc.y), ha.w, s);
          s = fmaf(u2lo(wc.z), hb.x, s); s = fmaf(u2hi(wc.z), hb.y, s);
          s = fmaf(u2lo(wc.w), hb.z, s); s = fmaf(u2hi(wc.w), hb.w, s);
          a[g] = s;
        }
      }
      if (t < TSTEPS && lane < 15) {
        float xv = xs[lane];
        #pragma unroll
        for (int g = 0; g < 4; ++g) a[g] = fmaf(wx[(wv << 2) + g][lane], xv, a[g]);
      }
    } else {                            // ---- layer1 @ t-1 : [Wih1|Whh1] . [h0[t-1];h1[t-2]]
      #pragma unroll
      for (int p = 0; p < 4; ++p) {
        int k = p * 512 + lane * 8;
        float4 ha = *(const float4*)(hcat + k);
        float4 hb = *(const float4*)(hcat + k + 4);
        #pragma unroll
        for (int g = 0; g < 4; ++g) {
          uint4 wc = *(const uint4*)(w1l + ((((wv - 2) << 2) + g) << 11) + k);
          float s = a[g];
          s = fmaf(u2lo(wc.x), ha.x, s); s = fmaf(u2hi(wc.x), ha.y, s);
          s = fmaf(u2lo(wc.y), ha.z, s); s = fmaf(u2hi(wc.y), ha.w, s);
          s = fmaf(u2lo(wc.z), hb.x, s); s = fmaf(u2hi(wc.z), hb.y, s);
          s = fmaf(u2lo(wc.w), hb.z, s); s = fmaf(u2hi(wc.w), hb.w, s);
          a[g] = s;
        }
      }
    }
    #pragma unroll
    for (int off = 32; off; off >>= 1) {
      #pragma unroll
      for (int g = 0; g < 4; ++g) a[g] += __shfl_xor(a[g], off);
    }
    if (lane == 0) {
      if (wv < 2) {
        if (t < TSTEPS) {
          float ii = sigm(a[0] + bs[0]), ff = sigm(a[1] + bs[1]);
          float gv = tanhf(a[2] + bs[2]), oo = sigm(a[3] + bs[3]);
          cc = ff * cc + ii * gv;
          hv = oo * tanhf(cc);
          h0buf[(t & 1) * HDIM + (b << 1) + wv] = hv;
        }
      } else {
        if (t > 0) {
          float ii = sigm(a[0] + bs[0]), ff = sigm(a[1] + bs[1]);
          float gv = tanhf(a[2] + bs[2]), oo = sigm(a[3] + bs[3]);
          cc = ff * cc + ii * gv;
          hv = oo * tanhf(cc);
          int u = (b << 1) + (wv - 2);
          h1buf[((t + 1) & 1) * HDIM + u] = hv;          // slot (t-1)&1
          hsbf[(size_t)(t - 1) * HDIM + u] = f2bfu(hv);
        }
      }
    }
    gpost(flagA, t + 1);
  }
  if (lane == 0) {
    if (wv < 2) { int u = (b << 1) + wv;       c0s[u] = cc; h0f[u] = hv; }
    else        { int u = (b << 1) + (wv - 2); c1s[u] = cc; h1f[u] = hv; }
  }
}

// ================= weight cast fp32 -> bf16 (lin0,lin1,W1,W2) =================
__global__ void cast_w(const float* __restrict__ linW, const float* __restrict__ W1m,
                       const float* __restrict__ W2m, bfu* __restrict__ wbf)
{
  int e4 = (blockIdx.x * 256 + threadIdx.x) * 4;   // < 4M
  int seg = e4 >> 20, off = e4 & 1048575;
  const float* src = (seg == 0) ? linW + off
                   : (seg == 1) ? linW + 1048576 + off
                   : (seg == 2) ? W1m + off : W2m + off;
  float4 v = *(const float4*)src;
  *(ushort4*)(wbf + e4) = pack4(v);
}

// ================= bf16 MFMA GEMM: Out[m][n] = leaky(sum_k A[m][k]*Bw[n][k] + bias[n]) =================
__global__ __launch_bounds__(256, 1) void mlp_gemm(
    const bfu* __restrict__ A, const bfu* __restrict__ Bw,
    const float* __restrict__ bias, bfu* __restrict__ Out)
{
  __shared__ bfu At[128 * 40];    // pitch 40 bf16 (pad)
  __shared__ bfu Bt[128 * 40];
  const int tid = threadIdx.x;
  const int bm = blockIdx.x * 128, bn = blockIdx.y * 128;
  const int wv = tid >> 6, lane = tid & 63;
  const int wm = (wv & 1) * 64, wn = (wv >> 1) * 64;
  const int m16 = lane & 15, q = lane >> 4;
  f32x4 acc[4][4];
  #pragma unroll
  for (int i = 0; i < 4; ++i)
    #pragma unroll
    for (int j = 0; j < 4; ++j) { f32x4 z = {0.f,0.f,0.f,0.f}; acc[i][j] = z; }

  for (int kt = 0; kt < 1024; kt += 32) {
    __syncthreads();
    #pragma unroll
    for (int i = 0; i < 2; ++i) {
      int idx = tid + i * 256;
      int r = idx >> 2, ch = idx & 3;
      *(uint4*)(At + r * 40 + ch * 8) = *(const uint4*)(A  + (size_t)(bm + r) * 1024 + kt + ch * 8);
      *(uint4*)(Bt + r * 40 + ch * 8) = *(const uint4*)(Bw + (size_t)(bn + r) * 1024 + kt + ch * 8);
    }
    __syncthreads();
    bf8v af[4], bfv[4];
    #pragma unroll
    for (int i = 0; i < 4; ++i) af[i]  = *(const bf8v*)(const void*)(At + (wm + i * 16 + m16) * 40 + q * 8);
    #pragma unroll
    for (int j = 0; j < 4; ++j) bfv[j] = *(const bf8v*)(const void*)(Bt + (wn + j * 16 + m16) * 40 + q * 8);
    #pragma unroll
    for (int i = 0; i < 4; ++i)
      #pragma unroll
      for (int j = 0; j < 4; ++j)
        acc[i][j] = __builtin_amdgcn_mfma_f32_16x16x32_bf16(af[i], bfv[j], acc[i][j], 0, 0, 0);
  }
  #pragma unroll
  for (int j = 0; j < 4; ++j) {
    int col = bn + wn + j * 16 + m16;
    float bv = bias[col];
    #pragma unroll
    for (int i = 0; i < 4; ++i) {
      #pragma unroll
      for (int r = 0; r < 4; ++r) {
        int row = bm + wm + i * 16 + q * 4 + r;   // C/D: col=lane&15, row=quad*4+reg
        float v = leaky(acc[i][j][r] + bv);
        Out[(size_t)row * 1024 + col] = f2bfu(v);
      }
    }
  }
}

// ================= Wo head: dout[t][o] = leaky(sum_k h[t][k]*Wo[o][k] + bo[o]) =================
__global__ void wo_ker(const bfu* __restrict__ Hb, const float* __restrict__ Wo,
                       const float* __restrict__ bo, float* __restrict__ dout,
                       float* __restrict__ outv)
{
  int tid = threadIdx.x;
  int t = blockIdx.x * 16 + (tid >> 4);
  int o = tid & 15;
  if (o == 15) return;
  const bfu* hr = Hb + (size_t)t * 1024;
  const float* wr = Wo + (size_t)o * 1024;
  float acc = 0.f;
  for (int k = 0; k < 1024; k += 8) {
    uint4 hc = *(const uint4*)(hr + k);
    float4 w0 = *(const float4*)(wr + k);
    float4 w1 = *(const float4*)(wr + k + 4);
    acc = fmaf(u2lo(hc.x), w0.x, acc); acc = fmaf(u2hi(hc.x), w0.y, acc);
    acc = fmaf(u2lo(hc.y), w0.z, acc); acc = fmaf(u2hi(hc.y), w0.w, acc);
    acc = fmaf(u2lo(hc.z), w1.x, acc); acc = fmaf(u2hi(hc.z), w1.y, acc);
    acc = fmaf(u2lo(hc.w), w1.z, acc); acc = fmaf(u2hi(hc.w), w1.w, acc);
  }
  acc = leaky(acc + bo[o]);
  dout[t * 15 + o] = acc;
  if (t == 8191) outv[o] = acc;
}

// ================= future steps (persistent, 256 blocks, 7 phases/step) =================
__device__ __forceinline__ float rowdot1024(const float* __restrict__ W,
                                            const float* __restrict__ v, int lane){
  float acc = 0.f;
  #pragma unroll
  for (int p = 0; p < 4; ++p) {
    int k = p * 256 + lane * 4;
    float4 w = *(const float4*)(W + k);
    float4 h = *(const float4*)(v + k);
    acc = fmaf(w.x, h.x, acc); acc = fmaf(w.y, h.y, acc);
    acc = fmaf(w.z, h.z, acc); acc = fmaf(w.w, h.w, acc);
  }
  #pragma unroll
  for (int off = 32; off; off >>= 1) acc += __shfl_xor(acc, off);
  return acc;
}

__global__ __launch_bounds__(256, 1) void future_seq(
    const float* __restrict__ Wih0, const float* __restrict__ Whh0,
    const float* __restrict__ bih0, const float* __restrict__ bhh0,
    const float* __restrict__ Wih1, const float* __restrict__ Whh1,
    const float* __restrict__ bih1, const float* __restrict__ bhh1,
    const float* __restrict__ linW, const float* __restrict__ linb,
    const float* __restrict__ W1m, const float* __restrict__ b1v,
    const float* __restrict__ W2m, const float* __restrict__ b2v,
    const float* __restrict__ Wo, const float* __restrict__ bo,
    float* __restrict__ h0fD, float* __restrict__ h1fD,
    const float* __restrict__ c0s, const float* __restrict__ c1s,
    float* __restrict__ v1, float* __restrict__ v2,
    float* __restrict__ v3, float* __restrict__ v4,
    float* __restrict__ outv, float* __restrict__ dout, int* __restrict__ flagD)
{
  __shared__ float vs[1024];
  __shared__ float vs2[1024];
  __shared__ float xsf[16];
  const int tid = threadIdx.x, b = blockIdx.x, wv = tid >> 6, lane = tid & 63;
  const int unit = (b << 2) + wv;
  float c0 = 0.f, c1 = 0.f;
  if (lane == 0) { c0 = c0s[unit]; c1 = c1s[unit]; }
  int pc = 0;
  for (int s = 0; s < FUT; ++s) {
    const int cur = s & 1, nxt = cur ^ 1;
    // ---- P1: layer0
    gwait(flagD, pc, 256);
    ((float4*)vs)[tid] = ((const float4*)(h0fD + cur * 1024))[tid];
    if (tid < 15) xsf[tid] = outv[tid];
    __syncthreads();
    float a[4];
    #pragma unroll
    for (int g = 0; g < 4; ++g)
      a[g] = rowdot1024(Whh0 + (size_t)((g << 10) + unit) * 1024, vs, lane);
    if (lane == 0) {
      float gg[4];
      #pragma unroll
      for (int g = 0; g < 4; ++g) {
        int R = (g << 10) + unit;
        float s15 = 0.f;
        for (int k = 0; k < 15; ++k) s15 = fmaf(Wih0[R * 15 + k], xsf[k], s15);
        gg[g] = a[g] + s15 + bih0[R] + bhh0[R];
      }
      float ii = sigm(gg[0]), ff = sigm(gg[1]), gv = tanhf(gg[2]), oo = sigm(gg[3]);
      c0 = ff * c0 + ii * gv;
      h0fD[nxt * 1024 + unit] = oo * tanhf(c0);
    }
    ++pc; gpost(flagD, pc);
    // ---- P2: layer1
    gwait(flagD, pc, 256);
    ((float4*)vs)[tid]  = ((const float4*)(h0fD + nxt * 1024))[tid];
    ((float4*)vs2)[tid] = ((const float4*)(h1fD + cur * 1024))[tid];
    __syncthreads();
    #pragma unroll
    for (int g = 0; g < 4; ++g) {
      int R = (g << 10) + unit;
      float acc = 0.f;
      #pragma unroll
      for (int p = 0; p < 4; ++p) {
        int k = p * 256 + lane * 4;
        float4 w = *(const float4*)(Wih1 + (size_t)R * 1024 + k);
        float4 h = *(const float4*)(vs + k);
        acc = fmaf(w.x, h.x, acc); acc = fmaf(w.y, h.y, acc);
        acc = fmaf(w.z, h.z, acc); acc = fmaf(w.w, h.w, acc);
        float4 w2 = *(const float4*)(Whh1 + (size_t)R * 1024 + k);
        float4 h2 = *(const float4*)(vs2 + k);
        acc = fmaf(w2.x, h2.x, acc); acc = fmaf(w2.y, h2.y, acc);
        acc = fmaf(w2.z, h2.z, acc); acc = fmaf(w2.w, h2.w, acc);
      }
      #pragma unroll
      for (int off = 32; off; off >>= 1) acc += __shfl_xor(acc, off);
      a[g] = acc;
    }
    if (lane == 0) {
      float gg[4];
      #pragma unroll
      for (int g = 0; g < 4; ++g) { int R = (g << 10) + unit; gg[g] = a[g] + bih1[R] + bhh1[R]; }
      float ii = sigm(gg[0]), ff = sigm(gg[1]), gv = tanhf(gg[2]), oo = sigm(gg[3]);
      c1 = ff * c1 + ii * gv;
      h1fD[nxt * 1024 + unit] = oo * tanhf(c1);
    }
    ++pc; gpost(flagD, pc);
    // ---- P3..P6: dense H->H layers
    for (int l = 0; l < 4; ++l) {
      const float* Wd = (l == 0) ? linW : (l == 1) ? linW + 1048576 : (l == 2) ? W1m : W2m;
      const float* bd = (l == 0) ? linb : (l == 1) ? linb + 1024 : (l == 2) ? b1v : b2v;
      const float* vin = (l == 0) ? (h1fD + nxt * 1024) : (l == 1) ? v1 : (l == 2) ? v2 : v3;
      float* vo = (l == 0) ? v1 : (l == 1) ? v2 : (l == 2) ? v3 : v4;
      gwait(flagD, pc, 256);
      ((float4*)vs)[tid] = ((const float4*)vin)[tid];
      __syncthreads();
      float acc = rowdot1024(Wd + (size_t)unit * 1024, vs, lane);
      if (lane == 0) vo[unit] = leaky(acc + bd[unit]);
      ++pc; gpost(flagD, pc);
    }
    // ---- P7: Wo head
    gwait(flagD, pc, 256);
    ((float4*)vs)[tid] = ((const float4*)v4)[tid];
    __syncthreads();
    if (b == 0) {
      for (int o = wv; o < 15; o += 4) {
        float acc = rowdot1024(Wo + (size_t)o * 1024, vs, lane);
        if (lane == 0) {
          float r = leaky(acc + bo[o]);
          dout[(8192 + s) * 15 + o] = r;
          outv[o] = r;
        }
      }
    }
    ++pc; gpost(flagD, pc);
  }
}

// ================= host =================
extern "C" void kernel_launch(void* const* d_in, const int* in_sizes, int n_in,
                              void* d_out, int out_size, void* d_ws, size_t ws_size,
                              hipStream_t stream)
{
  (void)in_sizes; (void)n_in; (void)out_size; (void)ws_size;
  const float* x    = (const float*)d_in[0];
  const float* Wih0 = (const float*)d_in[1];
  const float* Whh0 = (const float*)d_in[2];
  const float* bih0 = (const float*)d_in[3];
  const float* bhh0 = (const float*)d_in[4];
  const float* Wih1 = (const float*)d_in[5];
  const float* Whh1 = (const float*)d_in[6];
  const float* bih1 = (const float*)d_in[7];
  const float* bhh1 = (const float*)d_in[8];
  const float* linW = (const float*)d_in[9];
  const float* linb = (const float*)d_in[10];
  const float* W1m  = (const float*)d_in[11];
  const float* b1v  = (const float*)d_in[12];
  const float* W2m  = (const float*)d_in[13];
  const float* b2v  = (const float*)d_in[14];
  const float* Wo   = (const float*)d_in[15];
  const float* bo   = (const float*)d_in[16];
  float* dout = (float*)d_out;
  char*  ws   = (char*)d_ws;

  bfu* hsbf = (bfu*)(ws);                              // 8192x1024 bf16
  bfu* ping = (bfu*)(ws + (size_t)16777216);           // 8192x1024 bf16
  bfu* wbf  = (bfu*)(ws + (size_t)33554432);           // 4x1024x1024 bf16
  char* ctrl = ws + (size_t)41943040;
  int*   flagA = (int*)ctrl;                           // 512
  int*   flagD = (int*)(ctrl + 2048);                  // 256
  float* h0buf = (float*)(ctrl + 3072);                // 2x1024
  float* h1buf = (float*)(ctrl + 11264);               // 2x1024
  float* c0s   = (float*)(ctrl + 19456);
  float* c1s   = c0s + 1024;
  float* h0fD  = c1s + 1024;                           // 2x1024 (slot0 <- lstm_seq)
  float* h1fD  = h0fD + 2048;
  float* v1    = h1fD + 2048;
  float* v2    = v1 + 1024;
  float* v3    = v2 + 1024;
  float* v4    = v3 + 1024;
  float* outv  = v4 + 1024;

  hipMemsetAsync(ctrl, 0, 19456, stream);   // flags + h double-buffers

  cast_w<<<dim3(4096), dim3(256), 0, stream>>>(linW, W1m, W2m, wbf);

  lstm_seq<<<dim3(512), dim3(256), 0, stream>>>(
      x, Wih0, Whh0, bih0, bhh0, Wih1, Whh1, bih1, bhh1,
      hsbf, h0buf, h1buf, flagA, c0s, c1s, h0fD, h1fD);

  dim3 gg(64, 8), bb(256);
  mlp_gemm<<<gg, bb, 0, stream>>>(hsbf, wbf,           linb,        ping);
  mlp_gemm<<<gg, bb, 0, stream>>>(ping, wbf + 1048576, linb + 1024, hsbf);
  mlp_gemm<<<gg, bb, 0, stream>>>(hsbf, wbf + 2097152, b1v,         ping);
  mlp_gemm<<<gg, bb, 0, stream>>>(ping, wbf + 3145728, b2v,         hsbf);

  wo_ker<<<dim3(512), dim3(256), 0, stream>>>(hsbf, Wo, bo, dout, outv);

  future_seq<<<dim3(256), dim3(256), 0, stream>>>(
      Wih0, Whh0, bih0, bhh0, Wih1, Whh1, bih1, bhh1,
      linW, linb, W1m, b1v, W2m, b2v, Wo, bo,
      h0fD, h1fD, c0s, c1s, v1, v2, v3, v4, outv, dout, flagD);
}

// Round 2
// 67852.057 us; speedup vs baseline: 5.3642x; 5.3642x over previous
//
#include <hip/hip_runtime.h>
#include <hip/hip_bf16.h>

#define TSTEPS 8192
#define HDIM   1024
#define FUT    16

typedef unsigned short bfu;
typedef __bf16 bf8v  __attribute__((ext_vector_type(8)));
typedef float  f32x4 __attribute__((ext_vector_type(4)));

__device__ __forceinline__ float u2lo(unsigned u){ return __uint_as_float(u << 16); }
__device__ __forceinline__ float u2hi(unsigned u){ return __uint_as_float(u & 0xffff0000u); }
__device__ __forceinline__ bfu f2bfu(float f){
  unsigned u = __float_as_uint(f);
  return (bfu)((u + 0x7fffu + ((u >> 16) & 1u)) >> 16);   // RNE
}
__device__ __forceinline__ ushort4 pack4(float4 v){
  ushort4 p; p.x = f2bfu(v.x); p.y = f2bfu(v.y); p.z = f2bfu(v.z); p.w = f2bfu(v.w); return p;
}
__device__ __forceinline__ float leaky(float v){ return v >= 0.f ? v : 0.8f * v; }
__device__ __forceinline__ float sigm(float v){ return 1.f / (1.f + expf(-v)); }

// ======== device-coherent (sc1 / MALL) access primitives — NO cache fences ========
__device__ __forceinline__ void vmwait(){ asm volatile("s_waitcnt vmcnt(0)" ::: "memory"); }

__device__ __forceinline__ void st1c(float* p, float v){
  asm volatile("global_store_dword %0, %1, off sc1" :: "v"(p), "v"(v) : "memory");
}
__device__ __forceinline__ void stflag(int* p, int v){
  asm volatile("global_store_dword %0, %1, off sc1" :: "v"(p), "v"(v) : "memory");
}
__device__ __forceinline__ float ld1c(const float* p){
  float v;
  asm volatile("global_load_dword %0, %1, off sc1\n\ts_waitcnt vmcnt(0)"
               : "=v"(v) : "v"(p) : "memory");
  return v;
}
__device__ __forceinline__ f32x4 ld4c(const float* p){
  f32x4 v;
  asm volatile("global_load_dwordx4 %0, %1, off sc1\n\ts_waitcnt vmcnt(0)"
               : "=v"(v) : "v"(p) : "memory");
  return v;
}
__device__ __forceinline__ void ld8c(const float* p, f32x4& a, f32x4& b){
  asm volatile("global_load_dwordx4 %0, %2, off sc1\n\t"
               "global_load_dwordx4 %1, %2, off offset:16 sc1\n\t"
               "s_waitcnt vmcnt(0)"
               : "=&v"(a), "=&v"(b) : "v"(p) : "memory");
}
// lane polls flags[lane], [lane+64], [lane+128], [lane+192]
__device__ __forceinline__ void waitflag4(const int* p, int target){
  for (;;) {
    int v0, v1, v2, v3;
    asm volatile("global_load_dword %0, %4, off sc1\n\t"
                 "global_load_dword %1, %4, off offset:256 sc1\n\t"
                 "global_load_dword %2, %4, off offset:512 sc1\n\t"
                 "global_load_dword %3, %4, off offset:768 sc1\n\t"
                 "s_waitcnt vmcnt(0)"
                 : "=&v"(v0), "=&v"(v1), "=&v"(v2), "=&v"(v3) : "v"(p) : "memory");
    if (v0 >= target && v1 >= target && v2 >= target && v3 >= target) return;
    __builtin_amdgcn_s_sleep(1);
  }
}

// ================= persistent LSTM recurrence =================
// 256 blocks x 256 thr, 1 block/CU (LDS ~105KB). Block b owns L0 units
// 4b..4b+3 and L1 units 4b..4b+3; wave wv computes L0 unit 4b+wv AND L1
// unit 4b+wv (uniform, no divergence). Fused step t: layer0@t + layer1@(t-1).
// All cross-block state via sc1 (MALL-coherent) accesses; zero cache fences.
__global__ __launch_bounds__(256, 1) void lstm_seq(
    const float* __restrict__ x,
    const float* __restrict__ Wih0, const float* __restrict__ Whh0,
    const float* __restrict__ bih0, const float* __restrict__ bhh0,
    const float* __restrict__ Wih1, const float* __restrict__ Whh1,
    const float* __restrict__ bih1, const float* __restrict__ bhh1,
    bfu* __restrict__ hsbf, float* __restrict__ h0buf, float* __restrict__ h1buf,
    int* __restrict__ flagA,
    float* __restrict__ c0s, float* __restrict__ c1s,
    float* __restrict__ h0f, float* __restrict__ h1f)
{
  __shared__ bfu   w0l[16 * 1024];   // L0: 4 units x 4 gates x 1024 (bf16)
  __shared__ bfu   w1l[16 * 2048];   // L1: 4 units x 4 gates x [Wih1|Whh1]
  __shared__ float hcat[2048];       // [h0(t-1) | h1(t-2)] fp32
  __shared__ float xs[16];
  __shared__ float wx[16][16];       // Wih0 rows (15 cols), r = u*4+g

  const int tid  = threadIdx.x;
  const int b    = blockIdx.x;
  const int wv   = tid >> 6;
  const int lane = tid & 63;
  const int u    = (b << 2) + wv;

  // ---- one-time preload: weights fp32 -> bf16 into LDS ----
  for (int idx = tid * 4; idx < 16 * 1024; idx += 1024) {
    int r = idx >> 10, k = idx & 1023;
    int gr = ((r & 3) << 10) + (b << 2) + (r >> 2);
    float4 v = *(const float4*)(Whh0 + (size_t)gr * 1024 + k);
    *(ushort4*)(w0l + idx) = pack4(v);
  }
  for (int idx = tid * 4; idx < 16 * 2048; idx += 1024) {
    int r = idx >> 11, k = idx & 2047;
    int gr = ((r & 3) << 10) + (b << 2) + (r >> 2);
    float4 v = (k < 1024) ? *(const float4*)(Wih1 + (size_t)gr * 1024 + k)
                          : *(const float4*)(Whh1 + (size_t)gr * 1024 + (k - 1024));
    *(ushort4*)(w1l + idx) = pack4(v);
  }
  if (tid < 240) {
    int r = tid / 15, k = tid - r * 15;
    int gr = ((r & 3) << 10) + (b << 2) + (r >> 2);
    wx[r][k] = Wih0[gr * 15 + k];
  }
  float bs0[4], bs1[4];
  if (lane == 0) {
    #pragma unroll
    for (int g = 0; g < 4; ++g) {
      int gr = (g << 10) + u;
      bs0[g] = bih0[gr] + bhh0[gr];
      bs1[g] = bih1[gr] + bhh1[gr];
    }
  }
  float cc0 = 0.f, hv0 = 0.f, cc1 = 0.f, hv1 = 0.f;
  __syncthreads();

  for (int t = 0; t <= TSTEPS; ++t) {
    if (tid < 64) waitflag4(flagA + tid, t);
    __syncthreads();
    // stage h0[t-1], h1[t-2] into LDS via coherent loads
    {
      int base = tid * 8;
      const float* src = (tid < 128) ? (h0buf + ((t + 1) & 1) * HDIM + base)
                                     : (h1buf + (t & 1) * HDIM + (base - 1024));
      f32x4 va, vb;
      ld8c(src, va, vb);
      *(f32x4*)(hcat + base)     = va;
      *(f32x4*)(hcat + base + 4) = vb;
    }
    if (tid < 15 && t < TSTEPS) xs[tid] = x[t * 15 + tid];   // plain (L2-warm)
    __syncthreads();

    float a0[4] = {0.f, 0.f, 0.f, 0.f};
    float a1[4] = {0.f, 0.f, 0.f, 0.f};
    #pragma unroll
    for (int p = 0; p < 4; ++p) {
      int k = p * 512 + lane * 8;
      f32x4 ha = *(const f32x4*)(hcat + k);
      f32x4 hb = *(const f32x4*)(hcat + k + 4);
      if (p < 2) {                       // layer0 @ t : Whh0 . h0[t-1]
        #pragma unroll
        for (int g = 0; g < 4; ++g) {
          uint4 wc = *(const uint4*)(w0l + (((wv << 2) + g) << 10) + k);
          float s = a0[g];
          s = fmaf(u2lo(wc.x), ha.x, s); s = fmaf(u2hi(wc.x), ha.y, s);
          s = fmaf(u2lo(wc.y), ha.z, s); s = fmaf(u2hi(wc.y), ha.w, s);
          s = fmaf(u2lo(wc.z), hb.x, s); s = fmaf(u2hi(wc.z), hb.y, s);
          s = fmaf(u2lo(wc.w), hb.z, s); s = fmaf(u2hi(wc.w), hb.w, s);
          a0[g] = s;
        }
      }
      #pragma unroll
      for (int g = 0; g < 4; ++g) {      // layer1 @ t-1 : [Wih1|Whh1] . hcat
        uint4 wc = *(const uint4*)(w1l + (((wv << 2) + g) << 11) + k);
        float s = a1[g];
        s = fmaf(u2lo(wc.x), ha.x, s); s = fmaf(u2hi(wc.x), ha.y, s);
        s = fmaf(u2lo(wc.y), ha.z, s); s = fmaf(u2hi(wc.y), ha.w, s);
        s = fmaf(u2lo(wc.z), hb.x, s); s = fmaf(u2hi(wc.z), hb.y, s);
        s = fmaf(u2lo(wc.w), hb.z, s); s = fmaf(u2hi(wc.w), hb.w, s);
        a1[g] = s;
      }
    }
    if (t < TSTEPS && lane < 15) {
      float xv = xs[lane];
      #pragma unroll
      for (int g = 0; g < 4; ++g) a0[g] = fmaf(wx[(wv << 2) + g][lane], xv, a0[g]);
    }
    #pragma unroll
    for (int off = 32; off; off >>= 1) {
      #pragma unroll
      for (int g = 0; g < 4; ++g) {
        a0[g] += __shfl_xor(a0[g], off);
        a1[g] += __shfl_xor(a1[g], off);
      }
    }
    if (lane == 0) {
      if (t < TSTEPS) {
        float ii = sigm(a0[0] + bs0[0]), ff = sigm(a0[1] + bs0[1]);
        float gv = tanhf(a0[2] + bs0[2]), oo = sigm(a0[3] + bs0[3]);
        cc0 = ff * cc0 + ii * gv;
        hv0 = oo * tanhf(cc0);
        st1c(h0buf + (t & 1) * HDIM + u, hv0);
      }
      if (t > 0) {
        float ii = sigm(a1[0] + bs1[0]), ff = sigm(a1[1] + bs1[1]);
        float gv = tanhf(a1[2] + bs1[2]), oo = sigm(a1[3] + bs1[3]);
        cc1 = ff * cc1 + ii * gv;
        hv1 = oo * tanhf(cc1);
        st1c(h1buf + ((t + 1) & 1) * HDIM + u, hv1);       // slot (t-1)&1
        hsbf[(size_t)(t - 1) * HDIM + u] = f2bfu(hv1);     // plain stream
      }
      vmwait();    // h stores at MALL before this wave passes the barrier
    }
    __syncthreads();
    if (tid == 0) stflag(flagA + b, t + 1);
  }
  if (lane == 0) {           // plain stores; flushed at end-of-dispatch
    c0s[u] = cc0; h0f[u] = hv0;
    c1s[u] = cc1; h1f[u] = hv1;
  }
}

// ================= weight cast fp32 -> bf16 (lin0,lin1,W1,W2) =================
__global__ void cast_w(const float* __restrict__ linW, const float* __restrict__ W1m,
                       const float* __restrict__ W2m, bfu* __restrict__ wbf)
{
  int e4 = (blockIdx.x * 256 + threadIdx.x) * 4;   // < 4M
  int seg = e4 >> 20, off = e4 & 1048575;
  const float* src = (seg == 0) ? linW + off
                   : (seg == 1) ? linW + 1048576 + off
                   : (seg == 2) ? W1m + off : W2m + off;
  float4 v = *(const float4*)src;
  *(ushort4*)(wbf + e4) = pack4(v);
}

// ================= bf16 MFMA GEMM: Out[m][n] = leaky(sum_k A[m][k]*Bw[n][k] + bias[n]) =================
__global__ __launch_bounds__(256, 1) void mlp_gemm(
    const bfu* __restrict__ A, const bfu* __restrict__ Bw,
    const float* __restrict__ bias, bfu* __restrict__ Out)
{
  __shared__ bfu At[128 * 40];    // pitch 40 bf16 (pad)
  __shared__ bfu Bt[128 * 40];
  const int tid = threadIdx.x;
  const int bm = blockIdx.x * 128, bn = blockIdx.y * 128;
  const int wv = tid >> 6, lane = tid & 63;
  const int wm = (wv & 1) * 64, wn = (wv >> 1) * 64;
  const int m16 = lane & 15, q = lane >> 4;
  f32x4 acc[4][4];
  #pragma unroll
  for (int i = 0; i < 4; ++i)
    #pragma unroll
    for (int j = 0; j < 4; ++j) { f32x4 z = {0.f,0.f,0.f,0.f}; acc[i][j] = z; }

  for (int kt = 0; kt < 1024; kt += 32) {
    __syncthreads();
    #pragma unroll
    for (int i = 0; i < 2; ++i) {
      int idx = tid + i * 256;
      int r = idx >> 2, ch = idx & 3;
      *(uint4*)(At + r * 40 + ch * 8) = *(const uint4*)(A  + (size_t)(bm + r) * 1024 + kt + ch * 8);
      *(uint4*)(Bt + r * 40 + ch * 8) = *(const uint4*)(Bw + (size_t)(bn + r) * 1024 + kt + ch * 8);
    }
    __syncthreads();
    bf8v af[4], bfv[4];
    #pragma unroll
    for (int i = 0; i < 4; ++i) af[i]  = *(const bf8v*)(const void*)(At + (wm + i * 16 + m16) * 40 + q * 8);
    #pragma unroll
    for (int j = 0; j < 4; ++j) bfv[j] = *(const bf8v*)(const void*)(Bt + (wn + j * 16 + m16) * 40 + q * 8);
    #pragma unroll
    for (int i = 0; i < 4; ++i)
      #pragma unroll
      for (int j = 0; j < 4; ++j)
        acc[i][j] = __builtin_amdgcn_mfma_f32_16x16x32_bf16(af[i], bfv[j], acc[i][j], 0, 0, 0);
  }
  #pragma unroll
  for (int j = 0; j < 4; ++j) {
    int col = bn + wn + j * 16 + m16;
    float bv = bias[col];
    #pragma unroll
    for (int i = 0; i < 4; ++i) {
      #pragma unroll
      for (int r = 0; r < 4; ++r) {
        int row = bm + wm + i * 16 + q * 4 + r;   // C/D: col=lane&15, row=quad*4+reg
        float v = leaky(acc[i][j][r] + bv);
        Out[(size_t)row * 1024 + col] = f2bfu(v);
      }
    }
  }
}

// ================= Wo head: dout[t][o] = leaky(sum_k h[t][k]*Wo[o][k] + bo[o]) =================
__global__ void wo_ker(const bfu* __restrict__ Hb, const float* __restrict__ Wo,
                       const float* __restrict__ bo, float* __restrict__ dout,
                       float* __restrict__ outv)
{
  int tid = threadIdx.x;
  int t = blockIdx.x * 16 + (tid >> 4);
  int o = tid & 15;
  if (o == 15) return;
  const bfu* hr = Hb + (size_t)t * 1024;
  const float* wr = Wo + (size_t)o * 1024;
  float acc = 0.f;
  for (int k = 0; k < 1024; k += 8) {
    uint4 hc = *(const uint4*)(hr + k);
    float4 w0 = *(const float4*)(wr + k);
    float4 w1 = *(const float4*)(wr + k + 4);
    acc = fmaf(u2lo(hc.x), w0.x, acc); acc = fmaf(u2hi(hc.x), w0.y, acc);
    acc = fmaf(u2lo(hc.y), w0.z, acc); acc = fmaf(u2hi(hc.y), w0.w, acc);
    acc = fmaf(u2lo(hc.z), w1.x, acc); acc = fmaf(u2hi(hc.z), w1.y, acc);
    acc = fmaf(u2lo(hc.w), w1.z, acc); acc = fmaf(u2hi(hc.w), w1.w, acc);
  }
  acc = leaky(acc + bo[o]);
  dout[t * 15 + o] = acc;
  if (t == 8191) outv[o] = acc;
}

// ================= future steps (persistent, 256 blocks, 7 phases/step) =================
__device__ __forceinline__ float rowdot1024(const float* __restrict__ W,
                                            const float* __restrict__ v, int lane){
  float acc = 0.f;
  #pragma unroll
  for (int p = 0; p < 4; ++p) {
    int k = p * 256 + lane * 4;
    float4 w = *(const float4*)(W + k);
    float4 h = *(const float4*)(v + k);
    acc = fmaf(w.x, h.x, acc); acc = fmaf(w.y, h.y, acc);
    acc = fmaf(w.z, h.z, acc); acc = fmaf(w.w, h.w, acc);
  }
  #pragma unroll
  for (int off = 32; off; off >>= 1) acc += __shfl_xor(acc, off);
  return acc;
}

__global__ __launch_bounds__(256, 1) void future_seq(
    const float* __restrict__ Wih0, const float* __restrict__ Whh0,
    const float* __restrict__ bih0, const float* __restrict__ bhh0,
    const float* __restrict__ Wih1, const float* __restrict__ Whh1,
    const float* __restrict__ bih1, const float* __restrict__ bhh1,
    const float* __restrict__ linW, const float* __restrict__ linb,
    const float* __restrict__ W1m, const float* __restrict__ b1v,
    const float* __restrict__ W2m, const float* __restrict__ b2v,
    const float* __restrict__ Wo, const float* __restrict__ bo,
    float* __restrict__ h0fD, float* __restrict__ h1fD,
    const float* __restrict__ c0s, const float* __restrict__ c1s,
    float* __restrict__ v1, float* __restrict__ v2,
    float* __restrict__ v3, float* __restrict__ v4,
    float* __restrict__ outv, float* __restrict__ dout, int* __restrict__ flagD)
{
  __shared__ float vs[1024];
  __shared__ float vs2[1024];
  __shared__ float xsf[16];
  const int tid = threadIdx.x, b = blockIdx.x, wv = tid >> 6, lane = tid & 63;
  const int unit = (b << 2) + wv;
  float c0 = 0.f, c1 = 0.f;
  if (lane == 0) { c0 = c0s[unit]; c1 = c1s[unit]; }   // plain (prev dispatch)
  int pc = 0;
  for (int s = 0; s < FUT; ++s) {
    const int cur = s & 1, nxt = cur ^ 1;
    // ---- P1: layer0
    if (tid < 64) waitflag4(flagD + tid, pc);
    __syncthreads();
    ((f32x4*)vs)[tid] = ld4c(h0fD + cur * 1024 + tid * 4);
    if (tid < 15) xsf[tid] = ld1c(outv + tid);
    __syncthreads();
    float a[4];
    #pragma unroll
    for (int g = 0; g < 4; ++g)
      a[g] = rowdot1024(Whh0 + (size_t)((g << 10) + unit) * 1024, vs, lane);
    if (lane == 0) {
      float gg[4];
      #pragma unroll
      for (int g = 0; g < 4; ++g) {
        int R = (g << 10) + unit;
        float s15 = 0.f;
        for (int k = 0; k < 15; ++k) s15 = fmaf(Wih0[R * 15 + k], xsf[k], s15);
        gg[g] = a[g] + s15 + bih0[R] + bhh0[R];
      }
      float ii = sigm(gg[0]), ff = sigm(gg[1]), gv = tanhf(gg[2]), oo = sigm(gg[3]);
      c0 = ff * c0 + ii * gv;
      st1c(h0fD + nxt * 1024 + unit, oo * tanhf(c0));
      vmwait();
    }
    __syncthreads(); ++pc; if (tid == 0) stflag(flagD + b, pc);
    // ---- P2: layer1
    if (tid < 64) waitflag4(flagD + tid, pc);
    __syncthreads();
    ((f32x4*)vs)[tid]  = ld4c(h0fD + nxt * 1024 + tid * 4);
    ((f32x4*)vs2)[tid] = ld4c(h1fD + cur * 1024 + tid * 4);
    __syncthreads();
    #pragma unroll
    for (int g = 0; g < 4; ++g) {
      int R = (g << 10) + unit;
      float acc = 0.f;
      #pragma unroll
      for (int p = 0; p < 4; ++p) {
        int k = p * 256 + lane * 4;
        float4 w = *(const float4*)(Wih1 + (size_t)R * 1024 + k);
        float4 h = *(const float4*)(vs + k);
        acc = fmaf(w.x, h.x, acc); acc = fmaf(w.y, h.y, acc);
        acc = fmaf(w.z, h.z, acc); acc = fmaf(w.w, h.w, acc);
        float4 w2 = *(const float4*)(Whh1 + (size_t)R * 1024 + k);
        float4 h2 = *(const float4*)(vs2 + k);
        acc = fmaf(w2.x, h2.x, acc); acc = fmaf(w2.y, h2.y, acc);
        acc = fmaf(w2.z, h2.z, acc); acc = fmaf(w2.w, h2.w, acc);
      }
      #pragma unroll
      for (int off = 32; off; off >>= 1) acc += __shfl_xor(acc, off);
      a[g] = acc;
    }
    if (lane == 0) {
      float gg[4];
      #pragma unroll
      for (int g = 0; g < 4; ++g) { int R = (g << 10) + unit; gg[g] = a[g] + bih1[R] + bhh1[R]; }
      float ii = sigm(gg[0]), ff = sigm(gg[1]), gv = tanhf(gg[2]), oo = sigm(gg[3]);
      c1 = ff * c1 + ii * gv;
      st1c(h1fD + nxt * 1024 + unit, oo * tanhf(c1));
      vmwait();
    }
    __syncthreads(); ++pc; if (tid == 0) stflag(flagD + b, pc);
    // ---- P3..P6: dense H->H layers
    for (int l = 0; l < 4; ++l) {
      const float* Wd = (l == 0) ? linW : (l == 1) ? linW + 1048576 : (l == 2) ? W1m : W2m;
      const float* bd = (l == 0) ? linb : (l == 1) ? linb + 1024 : (l == 2) ? b1v : b2v;
      const float* vin = (l == 0) ? (h1fD + nxt * 1024) : (l == 1) ? v1 : (l == 2) ? v2 : v3;
      float* vo = (l == 0) ? v1 : (l == 1) ? v2 : (l == 2) ? v3 : v4;
      if (tid < 64) waitflag4(flagD + tid, pc);
      __syncthreads();
      ((f32x4*)vs)[tid] = ld4c(vin + tid * 4);
      __syncthreads();
      float acc = rowdot1024(Wd + (size_t)unit * 1024, vs, lane);
      if (lane == 0) { st1c(vo + unit, leaky(acc + bd[unit])); vmwait(); }
      __syncthreads(); ++pc; if (tid == 0) stflag(flagD + b, pc);
    }
    // ---- P7: Wo head
    if (tid < 64) waitflag4(flagD + tid, pc);
    __syncthreads();
    ((f32x4*)vs)[tid] = ld4c(v4 + tid * 4);
    __syncthreads();
    if (b == 0) {
      for (int o = wv; o < 15; o += 4) {
        float acc = rowdot1024(Wo + (size_t)o * 1024, vs, lane);
        if (lane == 0) {
          float r = leaky(acc + bo[o]);
          dout[(8192 + s) * 15 + o] = r;     // plain (output)
          st1c(outv + o, r);                 // coherent (consumed next step)
        }
      }
      if (lane == 0) vmwait();
    }
    __syncthreads(); ++pc; if (tid == 0) stflag(flagD + b, pc);
  }
}

// ================= host =================
extern "C" void kernel_launch(void* const* d_in, const int* in_sizes, int n_in,
                              void* d_out, int out_size, void* d_ws, size_t ws_size,
                              hipStream_t stream)
{
  (void)in_sizes; (void)n_in; (void)out_size; (void)ws_size;
  const float* x    = (const float*)d_in[0];
  const float* Wih0 = (const float*)d_in[1];
  const float* Whh0 = (const float*)d_in[2];
  const float* bih0 = (const float*)d_in[3];
  const float* bhh0 = (const float*)d_in[4];
  const float* Wih1 = (const float*)d_in[5];
  const float* Whh1 = (const float*)d_in[6];
  const float* bih1 = (const float*)d_in[7];
  const float* bhh1 = (const float*)d_in[8];
  const float* linW = (const float*)d_in[9];
  const float* linb = (const float*)d_in[10];
  const float* W1m  = (const float*)d_in[11];
  const float* b1v  = (const float*)d_in[12];
  const float* W2m  = (const float*)d_in[13];
  const float* b2v  = (const float*)d_in[14];
  const float* Wo   = (const float*)d_in[15];
  const float* bo   = (const float*)d_in[16];
  float* dout = (float*)d_out;
  char*  ws   = (char*)d_ws;

  bfu* hsbf = (bfu*)(ws);                              // 8192x1024 bf16
  bfu* ping = (bfu*)(ws + (size_t)16777216);           // 8192x1024 bf16
  bfu* wbf  = (bfu*)(ws + (size_t)33554432);           // 4x1024x1024 bf16
  char* ctrl = ws + (size_t)41943040;
  int*   flagA = (int*)ctrl;                           // 256 (pad to 2048B)
  int*   flagD = (int*)(ctrl + 2048);                  // 256
  float* h0buf = (float*)(ctrl + 3072);                // 2x1024
  float* h1buf = (float*)(ctrl + 11264);               // 2x1024
  float* c0s   = (float*)(ctrl + 19456);
  float* c1s   = c0s + 1024;
  float* h0fD  = c1s + 1024;                           // 2x1024 (slot0 <- lstm_seq)
  float* h1fD  = h0fD + 2048;
  float* v1    = h1fD + 2048;
  float* v2    = v1 + 1024;
  float* v3    = v2 + 1024;
  float* v4    = v3 + 1024;
  float* outv  = v4 + 1024;

  hipMemsetAsync(ctrl, 0, 19456, stream);   // flags + h double-buffers

  cast_w<<<dim3(4096), dim3(256), 0, stream>>>(linW, W1m, W2m, wbf);

  lstm_seq<<<dim3(256), dim3(256), 0, stream>>>(
      x, Wih0, Whh0, bih0, bhh0, Wih1, Whh1, bih1, bhh1,
      hsbf, h0buf, h1buf, flagA, c0s, c1s, h0fD, h1fD);

  dim3 gg(64, 8), bb(256);
  mlp_gemm<<<gg, bb, 0, stream>>>(hsbf, wbf,           linb,        ping);
  mlp_gemm<<<gg, bb, 0, stream>>>(ping, wbf + 1048576, linb + 1024, hsbf);
  mlp_gemm<<<gg, bb, 0, stream>>>(hsbf, wbf + 2097152, b1v,         ping);
  mlp_gemm<<<gg, bb, 0, stream>>>(ping, wbf + 3145728, b2v,         hsbf);

  wo_ker<<<dim3(512), dim3(256), 0, stream>>>(hsbf, Wo, bo, dout, outv);

  future_seq<<<dim3(256), dim3(256), 0, stream>>>(
      Wih0, Whh0, bih0, bhh0, Wih1, Whh1, bih1, bhh1,
      linW, linb, W1m, b1v, W2m, b2v, Wo, bo,
      h0fD, h1fD, c0s, c1s, v1, v2, v3, v4, outv, dout, flagD);
}